// Round 7
// baseline (303.119 us; speedup 1.0000x reference)
//
#include <hip/hip_runtime.h>
#include <stdint.h>

#define B_    8
#define N_    2048
#define INF_  128
#define H_    4
#define OUTF_ 32
#define BH_   (B_*H_)
#define ALPHA_ 0.2f

typedef __attribute__((ext_vector_type(8))) short bf16x8;
typedef __attribute__((ext_vector_type(4))) short bf16x4;
typedef __attribute__((ext_vector_type(4))) float f32x4;

static __device__ __forceinline__ short bf16_rne(float f) {
  uint32_t u = __float_as_uint(f);
  u += 0x7fffu + ((u >> 16) & 1u);
  return (short)(u >> 16);
}
// split f into bf16 hi (truncate) + bf16 lo (rne of residual): hi+lo ~ f to 2^-17
// macro (not ref-taking fn): vector elements can't bind to short&
#define BF16_SPLIT(f, dsthi, dstlo) {                         \
    const float f_ = (f);                                     \
    const uint32_t uh_ = __float_as_uint(f_) & 0xffff0000u;   \
    (dsthi) = (short)(uh_ >> 16);                             \
    (dstlo) = bf16_rne(f_ - __uint_as_float(uh_)); }

// ---------------- workspace layout (bytes) ----------------
// hThi  : bf16 [BH][32][N]   @ 0         (4 MB)
// hTlo  : bf16 [BH][32][N]   @ 4194304   (4 MB)
// bits  : u64  [N][N/64]     @ 8388608   (512 KB)
// Aarr..varr : f32 [BH][N] x6 @ 8912896  (1.5 MB)
// WThi  : bf16 [H][32][128]  @ 10485760  (32 KB)
// WTlo  : bf16 [H][32][128]  @ 10518528  (32 KB)

// ---------------- K0a: transpose W to split-bf16 WT[h][c][k] ----------------
__global__ void k_wt(const float* __restrict__ W, short* __restrict__ WThi,
                     short* __restrict__ WTlo) {
  const int h = blockIdx.x, k = threadIdx.x;  // 4 blocks x 128 threads
#pragma unroll
  for (int c = 0; c < OUTF_; ++c) {
    short hi, lo;
    BF16_SPLIT(W[(h * INF_ + k) * OUTF_ + c], hi, lo);
    WThi[(h * OUTF_ + c) * INF_ + k] = hi;
    WTlo[(h * OUTF_ + c) * INF_ + k] = lo;
  }
}

// ---------------- K0b: pack adjacency into 64-bit masks ----------------
__global__ __launch_bounds__(256) void k_pack_adj(const int* __restrict__ adj,
                                                  unsigned long long* __restrict__ bits) {
  const int i = blockIdx.x;
  const int t = threadIdx.x;
  const int* row = adj + (size_t)i * N_;
#pragma unroll
  for (int it = 0; it < N_ / 256; ++it) {
    const int j = it * 256 + t;
    const unsigned long long m = __ballot(row[j] != 0);
    if ((t & 63) == 0) bits[(size_t)i * (N_ / 64) + it * 4 + (t >> 6)] = m;
  }
}

// ---------------- K1: h = x@W via split-bf16 MFMA (fp32-accurate) ----------------
__global__ __launch_bounds__(256) void k_feat(const float* __restrict__ x,
    const short* __restrict__ WThi, const short* __restrict__ WTlo,
    const float* __restrict__ asrc, const float* __restrict__ adst,
    short* __restrict__ hThi, short* __restrict__ hTlo,
    float* __restrict__ Aarr, float* __restrict__ Barr, float* __restrict__ nsarr,
    float* __restrict__ darr, float* __restrict__ uarr, float* __restrict__ varr)
{
  const int t = threadIdx.x, lane = t & 63, wv = t >> 6;
  const int blk = blockIdx.x, bh = blk >> 5, itile = blk & 31;
  const int b = bh >> 2, hh = bh & 3;
  const int i0 = itile * 64 + wv * 16;
  const int cl = lane & 15, g = lane >> 4;

  const float* xr   = x + ((size_t)b * N_ + i0 + cl) * INF_ + g * 8;
  const size_t wo0 = (size_t)(hh * OUTF_ + cl) * INF_ + g * 8;
  const size_t wo1 = (size_t)(hh * OUTF_ + 16 + cl) * INF_ + g * 8;

  f32x4 acc0 = {0.f, 0.f, 0.f, 0.f}, acc1 = {0.f, 0.f, 0.f, 0.f};
#pragma unroll
  for (int kt = 0; kt < 4; ++kt) {
    const int kb = kt * 32;
    const f32x4 xa = *(const f32x4*)(xr + kb);
    const f32x4 xb = *(const f32x4*)(xr + kb + 4);
    bf16x8 ah, al;
    BF16_SPLIT(xa[0], ah[0], al[0]); BF16_SPLIT(xa[1], ah[1], al[1]);
    BF16_SPLIT(xa[2], ah[2], al[2]); BF16_SPLIT(xa[3], ah[3], al[3]);
    BF16_SPLIT(xb[0], ah[4], al[4]); BF16_SPLIT(xb[1], ah[5], al[5]);
    BF16_SPLIT(xb[2], ah[6], al[6]); BF16_SPLIT(xb[3], ah[7], al[7]);
    const bf16x8 b0h = *(const bf16x8*)(WThi + wo0 + kb);
    const bf16x8 b0l = *(const bf16x8*)(WTlo + wo0 + kb);
    const bf16x8 b1h = *(const bf16x8*)(WThi + wo1 + kb);
    const bf16x8 b1l = *(const bf16x8*)(WTlo + wo1 + kb);
    // (ah+al)(bh+bl) ~= ah*bh + al*bh + ah*bl  (al*bl ~ 2^-34, dropped)
    acc0 = __builtin_amdgcn_mfma_f32_16x16x32_bf16(ah, b0h, acc0, 0, 0, 0);
    acc0 = __builtin_amdgcn_mfma_f32_16x16x32_bf16(al, b0h, acc0, 0, 0, 0);
    acc0 = __builtin_amdgcn_mfma_f32_16x16x32_bf16(ah, b0l, acc0, 0, 0, 0);
    acc1 = __builtin_amdgcn_mfma_f32_16x16x32_bf16(ah, b1h, acc1, 0, 0, 0);
    acc1 = __builtin_amdgcn_mfma_f32_16x16x32_bf16(al, b1h, acc1, 0, 0, 0);
    acc1 = __builtin_amdgcn_mfma_f32_16x16x32_bf16(ah, b1l, acc1, 0, 0, 0);
  }

  // hT[bh][c][j]: C-frag rows (l>>4)*4+q are consecutive j -> 8B packed stores
  bf16x4 h0h, h0l, h1h, h1l;
  BF16_SPLIT(acc0[0], h0h[0], h0l[0]); BF16_SPLIT(acc0[1], h0h[1], h0l[1]);
  BF16_SPLIT(acc0[2], h0h[2], h0l[2]); BF16_SPLIT(acc0[3], h0h[3], h0l[3]);
  BF16_SPLIT(acc1[0], h1h[0], h1l[0]); BF16_SPLIT(acc1[1], h1h[1], h1l[1]);
  BF16_SPLIT(acc1[2], h1h[2], h1l[2]); BF16_SPLIT(acc1[3], h1h[3], h1l[3]);
  const size_t jw = (size_t)i0 + g * 4;
  const size_t c0 = ((size_t)bh * OUTF_ + cl) * N_ + jw;
  const size_t c1 = ((size_t)bh * OUTF_ + 16 + cl) * N_ + jw;
  *(bf16x4*)(hThi + c0) = h0h;
  *(bf16x4*)(hTlo + c0) = h0l;
  *(bf16x4*)(hThi + c1) = h1h;
  *(bf16x4*)(hTlo + c1) = h1l;

  // s_i = h_i . a_src, d_i = h_i . a_dst  (reduce over col dim = 16 lanes)
  const float as0 = asrc[hh * OUTF_ + cl], as1 = asrc[hh * OUTF_ + 16 + cl];
  const float ad0 = adst[hh * OUTF_ + cl], ad1 = adst[hh * OUTF_ + 16 + cl];
  float es0 = acc0[0] * as0 + acc1[0] * as1;
  float es1 = acc0[1] * as0 + acc1[1] * as1;
  float es2 = acc0[2] * as0 + acc1[2] * as1;
  float es3 = acc0[3] * as0 + acc1[3] * as1;
  float ed0 = acc0[0] * ad0 + acc1[0] * ad1;
  float ed1 = acc0[1] * ad0 + acc1[1] * ad1;
  float ed2 = acc0[2] * ad0 + acc1[2] * ad1;
  float ed3 = acc0[3] * ad0 + acc1[3] * ad1;
#pragma unroll
  for (int m = 1; m <= 8; m <<= 1) {
    es0 += __shfl_xor(es0, m); es1 += __shfl_xor(es1, m);
    es2 += __shfl_xor(es2, m); es3 += __shfl_xor(es3, m);
    ed0 += __shfl_xor(ed0, m); ed1 += __shfl_xor(ed1, m);
    ed2 += __shfl_xor(ed2, m); ed3 += __shfl_xor(ed3, m);
  }
  if (cl < 4) {
    const float s  = cl == 0 ? es0 : cl == 1 ? es1 : cl == 2 ? es2 : es3;
    const float dd = cl == 0 ? ed0 : cl == 1 ? ed1 : cl == 2 ? ed2 : ed3;
    const size_t ri = (size_t)bh * N_ + i0 + g * 4 + cl;
    Aarr[ri]  = expf(s);
    Barr[ri]  = expf(ALPHA_ * s);
    nsarr[ri] = -s;
    darr[ri]  = dd;
    uarr[ri]  = expf(dd);
    varr[ri]  = expf(ALPHA_ * dd);
  }
}

// ---------------- K3: fused masked-softmax @ h via MFMA ----------------
// 8 waves/block: waves 0-3 rows x j-half 0, waves 4-7 same rows x j-half 1.
// Partials combined via LDS. VGPR kept <=64 so 32 waves/CU is reachable
// (m69 cliff: waves/CU halves at 64 VGPR) -> grid 1024 x 8 waves = 8192 waves.
__global__ __launch_bounds__(512, 8) void k_attn(const short* __restrict__ hThi,
    const short* __restrict__ hTlo, const uint32_t* __restrict__ bits32,
    const float* __restrict__ Aarr, const float* __restrict__ Barr,
    const float* __restrict__ nsarr, const float* __restrict__ darr,
    const float* __restrict__ uarr, const float* __restrict__ varr,
    float* __restrict__ out)
{
  __shared__ float lred[4][64][9];   // waves 4-7 park acc(8) + z(1); stride 9 (coprime 32)

  const int t = threadIdx.x, lane = t & 63, wv = t >> 6;
  const int wq = wv & 3, half = wv >> 2;
  const int blk = blockIdx.x, bh = blk >> 5, itile = blk & 31;
  const int b = bh >> 2, hh = bh & 3;
  const int i0 = itile * 64 + wq * 16;   // 16 rows per wave
  const int cl = lane & 15, g = lane >> 4;
  const int jb = g * 8;

  const size_t rbase = (size_t)bh * N_;
  const float Ai  = Aarr[rbase + i0 + cl];
  const float Bi  = Barr[rbase + i0 + cl];
  const float nsi = nsarr[rbase + i0 + cl];
  const float* dg = darr + rbase;
  const float* ug = uarr + rbase;
  const float* vg = varr + rbase;
  const uint32_t* brow = bits32 + (size_t)(i0 + cl) * (N_ / 32);
  const size_t hc0 = ((size_t)bh * OUTF_ + cl) * N_;
  const size_t hc1 = ((size_t)bh * OUTF_ + 16 + cl) * N_;

  f32x4 acc0 = {0.f, 0.f, 0.f, 0.f}, acc1 = {0.f, 0.f, 0.f, 0.f};
  float z = 0.f;

#define WGEN(E, DE, UE, VE) {                                   \
    const bool c_ = (DE) > nsi;                                 \
    float w_ = (c_ ? Ai : Bi) * (c_ ? (UE) : (VE));             \
    w_ = ((wsh >> (E)) & 1u) ? w_ : 0.f;                        \
    const uint32_t hi_ = __float_as_uint(w_) & 0xffff0000u;     \
    whi[E] = (short)(hi_ >> 16);                                \
    wlo[E] = (short)(__float_as_uint(w_ - __uint_as_float(hi_)) >> 16); \
    z += w_; }

  const int jt0 = half * (N_ / 64);      // 32 j-tiles per half
#pragma unroll 2
  for (int jt = jt0; jt < jt0 + N_ / 64; ++jt) {
    const int j0 = jt * 32 + jb;
    const f32x4 d0 = *(const f32x4*)(dg + j0);
    const f32x4 d1 = *(const f32x4*)(dg + j0 + 4);
    const f32x4 u0 = *(const f32x4*)(ug + j0);
    const f32x4 u1 = *(const f32x4*)(ug + j0 + 4);
    const f32x4 v0 = *(const f32x4*)(vg + j0);
    const f32x4 v1 = *(const f32x4*)(vg + j0 + 4);
    const bf16x8 h0h = *(const bf16x8*)(hThi + hc0 + j0);
    const bf16x8 h0l = *(const bf16x8*)(hTlo + hc0 + j0);
    const bf16x8 h1h = *(const bf16x8*)(hThi + hc1 + j0);
    const bf16x8 h1l = *(const bf16x8*)(hTlo + hc1 + j0);
    const uint32_t wsh = brow[jt] >> jb;

    bf16x8 whi, wlo;
    WGEN(0, d0[0], u0[0], v0[0])
    WGEN(1, d0[1], u0[1], v0[1])
    WGEN(2, d0[2], u0[2], v0[2])
    WGEN(3, d0[3], u0[3], v0[3])
    WGEN(4, d1[0], u1[0], v1[0])
    WGEN(5, d1[1], u1[1], v1[1])
    WGEN(6, d1[2], u1[2], v1[2])
    WGEN(7, d1[3], u1[3], v1[3])

    // w*h ~= whi*hhi + wlo*hhi + whi*hlo  (fp32-equivalent numerator)
    acc0 = __builtin_amdgcn_mfma_f32_16x16x32_bf16(whi, h0h, acc0, 0, 0, 0);
    acc0 = __builtin_amdgcn_mfma_f32_16x16x32_bf16(wlo, h0h, acc0, 0, 0, 0);
    acc0 = __builtin_amdgcn_mfma_f32_16x16x32_bf16(whi, h0l, acc0, 0, 0, 0);
    acc1 = __builtin_amdgcn_mfma_f32_16x16x32_bf16(whi, h1h, acc1, 0, 0, 0);
    acc1 = __builtin_amdgcn_mfma_f32_16x16x32_bf16(wlo, h1h, acc1, 0, 0, 0);
    acc1 = __builtin_amdgcn_mfma_f32_16x16x32_bf16(whi, h1l, acc1, 0, 0, 0);
  }
#undef WGEN

  // fold z over the 4 j-groups within the wave (row = cl)
  z += __shfl_xor(z, 16);
  z += __shfl_xor(z, 32);

  // cross-wave combine: waves 4-7 park partials, waves 0-3 add them
  if (half == 1) {
    float* p = &lred[wq][lane][0];
    p[0] = acc0[0]; p[1] = acc0[1]; p[2] = acc0[2]; p[3] = acc0[3];
    p[4] = acc1[0]; p[5] = acc1[1]; p[6] = acc1[2]; p[7] = acc1[3];
    p[8] = z;
  }
  __syncthreads();
  if (half == 1) return;

  {
    const float* p = &lred[wq][lane][0];
    acc0[0] += p[0]; acc0[1] += p[1]; acc0[2] += p[2]; acc0[3] += p[3];
    acc1[0] += p[4]; acc1[1] += p[5]; acc1[2] += p[6]; acc1[3] += p[7];
    z += p[8];
  }

  // epilogue: C-frag row = g*4+q, col = cl; fetch that row's Z via shfl
  float* op = out + ((size_t)b * N_ + i0) * (H_ * OUTF_) + hh * OUTF_;
#pragma unroll
  for (int q = 0; q < 4; ++q) {
    const float zr = __shfl(z, g * 4 + q);
    const float inv = 1.0f / zr;
    op[(size_t)(g * 4 + q) * (H_ * OUTF_) + cl]      = acc0[q] * inv;
    op[(size_t)(g * 4 + q) * (H_ * OUTF_) + 16 + cl] = acc1[q] * inv;
  }
}

extern "C" void kernel_launch(void* const* d_in, const int* in_sizes, int n_in,
                              void* d_out, int out_size, void* d_ws, size_t ws_size,
                              hipStream_t stream) {
  const float* x    = (const float*)d_in[0];
  const int*   adj  = (const int*)d_in[1];
  const float* W    = (const float*)d_in[2];
  const float* asrc = (const float*)d_in[3];
  const float* adst = (const float*)d_in[4];
  float* out = (float*)d_out;

  char* ws = (char*)d_ws;
  short* hThi = (short*)ws;                                         // 4 MB
  short* hTlo = (short*)(ws + 4194304);                             // 4 MB
  unsigned long long* bits = (unsigned long long*)(ws + 8388608);   // 512 KB
  float* Aarr  = (float*)(ws + 8912896);
  float* Barr  = Aarr  + BH_ * N_;
  float* nsarr = Barr  + BH_ * N_;
  float* darr  = nsarr + BH_ * N_;
  float* uarr  = darr  + BH_ * N_;
  float* varr  = uarr  + BH_ * N_;
  short* WThi  = (short*)(ws + 10485760);                           // 32 KB
  short* WTlo  = (short*)(ws + 10518528);                           // 32 KB

  hipLaunchKernelGGL(k_wt, dim3(H_), dim3(INF_), 0, stream, W, WThi, WTlo);
  hipLaunchKernelGGL(k_pack_adj, dim3(N_), dim3(256), 0, stream, adj, bits);
  hipLaunchKernelGGL(k_feat, dim3(BH_ * 32), dim3(256), 0, stream,
                     x, WThi, WTlo, asrc, adst, hThi, hTlo,
                     Aarr, Barr, nsarr, darr, uarr, varr);
  hipLaunchKernelGGL(k_attn, dim3(BH_ * 32), dim3(512), 0, stream,
                     hThi, hTlo, (const uint32_t*)bits,
                     Aarr, Barr, nsarr, darr, uarr, varr, out);
}

// Round 8
// 278.321 us; speedup vs baseline: 1.0891x; 1.0891x over previous
//
#include <hip/hip_runtime.h>
#include <stdint.h>

#define B_    8
#define N_    2048
#define INF_  128
#define H_    4
#define OUTF_ 32
#define BH_   (B_*H_)
#define ALPHA_ 0.2f

typedef __attribute__((ext_vector_type(8))) short bf16x8;
typedef __attribute__((ext_vector_type(4))) short bf16x4;
typedef __attribute__((ext_vector_type(4))) float f32x4;

static __device__ __forceinline__ short bf16_rne(float f) {
  uint32_t u = __float_as_uint(f);
  u += 0x7fffu + ((u >> 16) & 1u);
  return (short)(u >> 16);
}
// split f into bf16 hi (truncate) + bf16 lo (rne of residual): hi+lo ~ f to 2^-17
// macro (not ref-taking fn): vector elements can't bind to short&
#define BF16_SPLIT(f, dsthi, dstlo) {                         \
    const float f_ = (f);                                     \
    const uint32_t uh_ = __float_as_uint(f_) & 0xffff0000u;   \
    (dsthi) = (short)(uh_ >> 16);                             \
    (dstlo) = bf16_rne(f_ - __uint_as_float(uh_)); }

// ---------------- workspace layout (bytes) ----------------
// hThi  : bf16 [BH][32][N]   @ 0         (4 MB)
// hTlo  : bf16 [BH][32][N]   @ 4194304   (4 MB)
// bits  : u64  [N][N/64]     @ 8388608   (512 KB)
// Aarr..varr : f32 [BH][N] x6 @ 8912896  (1.5 MB)
// WThi  : bf16 [H][32][128]  @ 10485760  (32 KB)
// WTlo  : bf16 [H][32][128]  @ 10518528  (32 KB)

// ---------------- K0a: transpose W to split-bf16 WT[h][c][k] ----------------
__global__ void k_wt(const float* __restrict__ W, short* __restrict__ WThi,
                     short* __restrict__ WTlo) {
  const int h = blockIdx.x, k = threadIdx.x;  // 4 blocks x 128 threads
#pragma unroll
  for (int c = 0; c < OUTF_; ++c) {
    short hi, lo;
    BF16_SPLIT(W[(h * INF_ + k) * OUTF_ + c], hi, lo);
    WThi[(h * OUTF_ + c) * INF_ + k] = hi;
    WTlo[(h * OUTF_ + c) * INF_ + k] = lo;
  }
}

// ---------------- K0b: pack adjacency into 64-bit masks ----------------
__global__ __launch_bounds__(256) void k_pack_adj(const int* __restrict__ adj,
                                                  unsigned long long* __restrict__ bits) {
  const int i = blockIdx.x;
  const int t = threadIdx.x;
  const int* row = adj + (size_t)i * N_;
#pragma unroll
  for (int it = 0; it < N_ / 256; ++it) {
    const int j = it * 256 + t;
    const unsigned long long m = __ballot(row[j] != 0);
    if ((t & 63) == 0) bits[(size_t)i * (N_ / 64) + it * 4 + (t >> 6)] = m;
  }
}

// ---------------- K1: h = x@W via split-bf16 MFMA (fp32-accurate) ----------------
__global__ __launch_bounds__(256) void k_feat(const float* __restrict__ x,
    const short* __restrict__ WThi, const short* __restrict__ WTlo,
    const float* __restrict__ asrc, const float* __restrict__ adst,
    short* __restrict__ hThi, short* __restrict__ hTlo,
    float* __restrict__ Aarr, float* __restrict__ Barr, float* __restrict__ nsarr,
    float* __restrict__ darr, float* __restrict__ uarr, float* __restrict__ varr)
{
  const int t = threadIdx.x, lane = t & 63, wv = t >> 6;
  const int blk = blockIdx.x, bh = blk >> 5, itile = blk & 31;
  const int b = bh >> 2, hh = bh & 3;
  const int i0 = itile * 64 + wv * 16;
  const int cl = lane & 15, g = lane >> 4;

  const float* xr   = x + ((size_t)b * N_ + i0 + cl) * INF_ + g * 8;
  const size_t wo0 = (size_t)(hh * OUTF_ + cl) * INF_ + g * 8;
  const size_t wo1 = (size_t)(hh * OUTF_ + 16 + cl) * INF_ + g * 8;

  f32x4 acc0 = {0.f, 0.f, 0.f, 0.f}, acc1 = {0.f, 0.f, 0.f, 0.f};
#pragma unroll
  for (int kt = 0; kt < 4; ++kt) {
    const int kb = kt * 32;
    const f32x4 xa = *(const f32x4*)(xr + kb);
    const f32x4 xb = *(const f32x4*)(xr + kb + 4);
    bf16x8 ah, al;
    BF16_SPLIT(xa[0], ah[0], al[0]); BF16_SPLIT(xa[1], ah[1], al[1]);
    BF16_SPLIT(xa[2], ah[2], al[2]); BF16_SPLIT(xa[3], ah[3], al[3]);
    BF16_SPLIT(xb[0], ah[4], al[4]); BF16_SPLIT(xb[1], ah[5], al[5]);
    BF16_SPLIT(xb[2], ah[6], al[6]); BF16_SPLIT(xb[3], ah[7], al[7]);
    const bf16x8 b0h = *(const bf16x8*)(WThi + wo0 + kb);
    const bf16x8 b0l = *(const bf16x8*)(WTlo + wo0 + kb);
    const bf16x8 b1h = *(const bf16x8*)(WThi + wo1 + kb);
    const bf16x8 b1l = *(const bf16x8*)(WTlo + wo1 + kb);
    // (ah+al)(bh+bl) ~= ah*bh + al*bh + ah*bl  (al*bl ~ 2^-34, dropped)
    acc0 = __builtin_amdgcn_mfma_f32_16x16x32_bf16(ah, b0h, acc0, 0, 0, 0);
    acc0 = __builtin_amdgcn_mfma_f32_16x16x32_bf16(al, b0h, acc0, 0, 0, 0);
    acc0 = __builtin_amdgcn_mfma_f32_16x16x32_bf16(ah, b0l, acc0, 0, 0, 0);
    acc1 = __builtin_amdgcn_mfma_f32_16x16x32_bf16(ah, b1h, acc1, 0, 0, 0);
    acc1 = __builtin_amdgcn_mfma_f32_16x16x32_bf16(al, b1h, acc1, 0, 0, 0);
    acc1 = __builtin_amdgcn_mfma_f32_16x16x32_bf16(ah, b1l, acc1, 0, 0, 0);
  }

  // hT[bh][c][j]: C-frag rows (l>>4)*4+q are consecutive j -> 8B packed stores
  bf16x4 h0h, h0l, h1h, h1l;
  BF16_SPLIT(acc0[0], h0h[0], h0l[0]); BF16_SPLIT(acc0[1], h0h[1], h0l[1]);
  BF16_SPLIT(acc0[2], h0h[2], h0l[2]); BF16_SPLIT(acc0[3], h0h[3], h0l[3]);
  BF16_SPLIT(acc1[0], h1h[0], h1l[0]); BF16_SPLIT(acc1[1], h1h[1], h1l[1]);
  BF16_SPLIT(acc1[2], h1h[2], h1l[2]); BF16_SPLIT(acc1[3], h1h[3], h1l[3]);
  const size_t jw = (size_t)i0 + g * 4;
  const size_t c0 = ((size_t)bh * OUTF_ + cl) * N_ + jw;
  const size_t c1 = ((size_t)bh * OUTF_ + 16 + cl) * N_ + jw;
  *(bf16x4*)(hThi + c0) = h0h;
  *(bf16x4*)(hTlo + c0) = h0l;
  *(bf16x4*)(hThi + c1) = h1h;
  *(bf16x4*)(hTlo + c1) = h1l;

  // s_i = h_i . a_src, d_i = h_i . a_dst  (reduce over col dim = 16 lanes)
  const float as0 = asrc[hh * OUTF_ + cl], as1 = asrc[hh * OUTF_ + 16 + cl];
  const float ad0 = adst[hh * OUTF_ + cl], ad1 = adst[hh * OUTF_ + 16 + cl];
  float es0 = acc0[0] * as0 + acc1[0] * as1;
  float es1 = acc0[1] * as0 + acc1[1] * as1;
  float es2 = acc0[2] * as0 + acc1[2] * as1;
  float es3 = acc0[3] * as0 + acc1[3] * as1;
  float ed0 = acc0[0] * ad0 + acc1[0] * ad1;
  float ed1 = acc0[1] * ad0 + acc1[1] * ad1;
  float ed2 = acc0[2] * ad0 + acc1[2] * ad1;
  float ed3 = acc0[3] * ad0 + acc1[3] * ad1;
#pragma unroll
  for (int m = 1; m <= 8; m <<= 1) {
    es0 += __shfl_xor(es0, m); es1 += __shfl_xor(es1, m);
    es2 += __shfl_xor(es2, m); es3 += __shfl_xor(es3, m);
    ed0 += __shfl_xor(ed0, m); ed1 += __shfl_xor(ed1, m);
    ed2 += __shfl_xor(ed2, m); ed3 += __shfl_xor(ed3, m);
  }
  if (cl < 4) {
    const float s  = cl == 0 ? es0 : cl == 1 ? es1 : cl == 2 ? es2 : es3;
    const float dd = cl == 0 ? ed0 : cl == 1 ? ed1 : cl == 2 ? ed2 : ed3;
    const size_t ri = (size_t)bh * N_ + i0 + g * 4 + cl;
    Aarr[ri]  = expf(s);
    Barr[ri]  = expf(ALPHA_ * s);
    nsarr[ri] = -s;
    darr[ri]  = dd;
    uarr[ri]  = expf(dd);
    varr[ri]  = expf(ALPHA_ * dd);
  }
}

// ---------------- K3: fused masked-softmax @ h via MFMA ----------------
// 4 waves/block, 1024 blocks (= 16 waves/CU, grid-capped). launch_bounds(256,4)
// grants <=128 VGPR (no spill; R7's (512,8) forced VGPR=32 -> 43MB scratch).
// Register double-buffer: load tile jt+1 into the idle buffer while computing
// jt, so the ~10 L1/L2 loads stop serializing (R6: VALU 24% = ~10 x 300cyc
// sequential stalls/iter).
typedef struct {
  f32x4 d0, d1, u0, u1, v0, v1;
  bf16x8 h0h, h0l, h1h, h1l;
  uint32_t msk;
} Tile;

__global__ __launch_bounds__(256, 4) void k_attn(const short* __restrict__ hThi,
    const short* __restrict__ hTlo, const uint32_t* __restrict__ bits32,
    const float* __restrict__ Aarr, const float* __restrict__ Barr,
    const float* __restrict__ nsarr, const float* __restrict__ darr,
    const float* __restrict__ uarr, const float* __restrict__ varr,
    float* __restrict__ out)
{
  const int t = threadIdx.x, lane = t & 63, wv = t >> 6;
  const int blk = blockIdx.x, bh = blk >> 5, itile = blk & 31;
  const int b = bh >> 2, hh = bh & 3;
  const int i0 = itile * 64 + wv * 16;   // 16 rows per wave
  const int cl = lane & 15, g = lane >> 4;
  const int jb = g * 8;

  const size_t rbase = (size_t)bh * N_;
  const float Ai  = Aarr[rbase + i0 + cl];
  const float Bi  = Barr[rbase + i0 + cl];
  const float nsi = nsarr[rbase + i0 + cl];
  const float* dg = darr + rbase;
  const float* ug = uarr + rbase;
  const float* vg = varr + rbase;
  const uint32_t* brow = bits32 + (size_t)(i0 + cl) * (N_ / 32);
  const size_t hc0 = ((size_t)bh * OUTF_ + cl) * N_;
  const size_t hc1 = ((size_t)bh * OUTF_ + 16 + cl) * N_;

  f32x4 acc0 = {0.f, 0.f, 0.f, 0.f}, acc1 = {0.f, 0.f, 0.f, 0.f};
  float z = 0.f;

#define LOADT(T, JT) {                                      \
    const int j0_ = (JT) * 32 + jb;                         \
    T.d0 = *(const f32x4*)(dg + j0_);                       \
    T.d1 = *(const f32x4*)(dg + j0_ + 4);                   \
    T.u0 = *(const f32x4*)(ug + j0_);                       \
    T.u1 = *(const f32x4*)(ug + j0_ + 4);                   \
    T.v0 = *(const f32x4*)(vg + j0_);                       \
    T.v1 = *(const f32x4*)(vg + j0_ + 4);                   \
    T.h0h = *(const bf16x8*)(hThi + hc0 + j0_);             \
    T.h0l = *(const bf16x8*)(hTlo + hc0 + j0_);             \
    T.h1h = *(const bf16x8*)(hThi + hc1 + j0_);             \
    T.h1l = *(const bf16x8*)(hTlo + hc1 + j0_);             \
    T.msk = brow[JT]; }

#define WGEN(E, DE, UE, VE) {                                   \
    const bool c_ = (DE) > nsi;                                 \
    float w_ = (c_ ? Ai : Bi) * (c_ ? (UE) : (VE));             \
    w_ = ((wsh >> (E)) & 1u) ? w_ : 0.f;                        \
    const uint32_t hi_ = __float_as_uint(w_) & 0xffff0000u;     \
    whi[E] = (short)(hi_ >> 16);                                \
    wlo[E] = (short)(__float_as_uint(w_ - __uint_as_float(hi_)) >> 16); \
    z += w_; }

#define COMPUTE(T) {                                            \
    const uint32_t wsh = T.msk >> jb;                           \
    bf16x8 whi, wlo;                                            \
    WGEN(0, T.d0[0], T.u0[0], T.v0[0])                          \
    WGEN(1, T.d0[1], T.u0[1], T.v0[1])                          \
    WGEN(2, T.d0[2], T.u0[2], T.v0[2])                          \
    WGEN(3, T.d0[3], T.u0[3], T.v0[3])                          \
    WGEN(4, T.d1[0], T.u1[0], T.v1[0])                          \
    WGEN(5, T.d1[1], T.u1[1], T.v1[1])                          \
    WGEN(6, T.d1[2], T.u1[2], T.v1[2])                          \
    WGEN(7, T.d1[3], T.u1[3], T.v1[3])                          \
    acc0 = __builtin_amdgcn_mfma_f32_16x16x32_bf16(whi, T.h0h, acc0, 0, 0, 0); \
    acc0 = __builtin_amdgcn_mfma_f32_16x16x32_bf16(wlo, T.h0h, acc0, 0, 0, 0); \
    acc0 = __builtin_amdgcn_mfma_f32_16x16x32_bf16(whi, T.h0l, acc0, 0, 0, 0); \
    acc1 = __builtin_amdgcn_mfma_f32_16x16x32_bf16(whi, T.h1h, acc1, 0, 0, 0); \
    acc1 = __builtin_amdgcn_mfma_f32_16x16x32_bf16(wlo, T.h1h, acc1, 0, 0, 0); \
    acc1 = __builtin_amdgcn_mfma_f32_16x16x32_bf16(whi, T.h1l, acc1, 0, 0, 0); }

  Tile ta, tb;
  LOADT(ta, 0)
#pragma unroll 1
  for (int jt = 0; jt < N_ / 32; jt += 2) {
    LOADT(tb, jt + 1)          // prefetch odd tile while computing even
    COMPUTE(ta)
    if (jt + 2 < N_ / 32) LOADT(ta, jt + 2)   // prefetch next even
    COMPUTE(tb)
  }
#undef COMPUTE
#undef WGEN
#undef LOADT

  // fold z over the 4 j-groups within the wave (row = cl)
  z += __shfl_xor(z, 16);
  z += __shfl_xor(z, 32);

  // epilogue: C-frag row = g*4+q, col = cl; fetch that row's Z via shfl
  float* op = out + ((size_t)b * N_ + i0) * (H_ * OUTF_) + hh * OUTF_;
#pragma unroll
  for (int q = 0; q < 4; ++q) {
    const float zr = __shfl(z, g * 4 + q);
    const float inv = 1.0f / zr;
    op[(size_t)(g * 4 + q) * (H_ * OUTF_) + cl]      = acc0[q] * inv;
    op[(size_t)(g * 4 + q) * (H_ * OUTF_) + 16 + cl] = acc1[q] * inv;
  }
}

extern "C" void kernel_launch(void* const* d_in, const int* in_sizes, int n_in,
                              void* d_out, int out_size, void* d_ws, size_t ws_size,
                              hipStream_t stream) {
  const float* x    = (const float*)d_in[0];
  const int*   adj  = (const int*)d_in[1];
  const float* W    = (const float*)d_in[2];
  const float* asrc = (const float*)d_in[3];
  const float* adst = (const float*)d_in[4];
  float* out = (float*)d_out;

  char* ws = (char*)d_ws;
  short* hThi = (short*)ws;                                         // 4 MB
  short* hTlo = (short*)(ws + 4194304);                             // 4 MB
  unsigned long long* bits = (unsigned long long*)(ws + 8388608);   // 512 KB
  float* Aarr  = (float*)(ws + 8912896);
  float* Barr  = Aarr  + BH_ * N_;
  float* nsarr = Barr  + BH_ * N_;
  float* darr  = nsarr + BH_ * N_;
  float* uarr  = darr  + BH_ * N_;
  float* varr  = uarr  + BH_ * N_;
  short* WThi  = (short*)(ws + 10485760);                           // 32 KB
  short* WTlo  = (short*)(ws + 10518528);                           // 32 KB

  hipLaunchKernelGGL(k_wt, dim3(H_), dim3(INF_), 0, stream, W, WThi, WTlo);
  hipLaunchKernelGGL(k_pack_adj, dim3(N_), dim3(256), 0, stream, adj, bits);
  hipLaunchKernelGGL(k_feat, dim3(BH_ * 32), dim3(256), 0, stream,
                     x, WThi, WTlo, asrc, adst, hThi, hTlo,
                     Aarr, Barr, nsarr, darr, uarr, varr);
  hipLaunchKernelGGL(k_attn, dim3(BH_ * 32), dim3(256), 0, stream,
                     hThi, hTlo, (const uint32_t*)bits,
                     Aarr, Barr, nsarr, darr, uarr, varr, out);
}

// Round 12
// 149.291 us; speedup vs baseline: 2.0304x; 1.8643x over previous
//
#include <hip/hip_runtime.h>
#include <stdint.h>

#define B_    8
#define N_    2048
#define INF_  128
#define H_    4
#define OUTF_ 32
#define BH_   (B_*H_)
#define ALPHA_ 0.2f

typedef __attribute__((ext_vector_type(8))) short bf16x8;
typedef __attribute__((ext_vector_type(4))) short bf16x4;
typedef __attribute__((ext_vector_type(4))) float f32x4;

static __device__ __forceinline__ short bf16_rne(float f) {
  uint32_t u = __float_as_uint(f);
  u += 0x7fffu + ((u >> 16) & 1u);
  return (short)(u >> 16);
}
// split f into bf16 hi (truncate) + bf16 lo (rne of residual): hi+lo ~ f to 2^-17
// macro (not ref-taking fn): vector elements can't bind to short&
#define BF16_SPLIT(f, dsthi, dstlo) {                         \
    const float f_ = (f);                                     \
    const uint32_t uh_ = __float_as_uint(f_) & 0xffff0000u;   \
    (dsthi) = (short)(uh_ >> 16);                             \
    (dstlo) = bf16_rne(f_ - __uint_as_float(uh_)); }

// ---------------- workspace layout (bytes) ----------------
// hThi  : bf16 [BH][32][N]   @ 0         (4 MB)
// hTlo  : bf16 [BH][32][N]   @ 4194304   (4 MB)
// bits  : u64  [N][N/64]     @ 8388608   (512 KB)
// Aarr..varr : f32 [BH][N] x6 @ 8912896  (1.5 MB)
// WThi  : bf16 [H][32][128]  @ 10485760  (32 KB)
// WTlo  : bf16 [H][32][128]  @ 10518528  (32 KB)

// ---------------- K0a: transpose W to split-bf16 WT[h][c][k] ----------------
__global__ void k_wt(const float* __restrict__ W, short* __restrict__ WThi,
                     short* __restrict__ WTlo) {
  const int h = blockIdx.x, k = threadIdx.x;  // 4 blocks x 128 threads
#pragma unroll
  for (int c = 0; c < OUTF_; ++c) {
    short hi, lo;
    BF16_SPLIT(W[(h * INF_ + k) * OUTF_ + c], hi, lo);
    WThi[(h * OUTF_ + c) * INF_ + k] = hi;
    WTlo[(h * OUTF_ + c) * INF_ + k] = lo;
  }
}

// ---------------- K0b: pack adjacency into 64-bit masks ----------------
__global__ __launch_bounds__(256) void k_pack_adj(const int* __restrict__ adj,
                                                  unsigned long long* __restrict__ bits) {
  const int i = blockIdx.x;
  const int t = threadIdx.x;
  const int* row = adj + (size_t)i * N_;
#pragma unroll
  for (int it = 0; it < N_ / 256; ++it) {
    const int j = it * 256 + t;
    const unsigned long long m = __ballot(row[j] != 0);
    if ((t & 63) == 0) bits[(size_t)i * (N_ / 64) + it * 4 + (t >> 6)] = m;
  }
}

// ---------------- K1: h = x@W via split-bf16 MFMA (fp32-accurate) ----------------
__global__ __launch_bounds__(256) void k_feat(const float* __restrict__ x,
    const short* __restrict__ WThi, const short* __restrict__ WTlo,
    const float* __restrict__ asrc, const float* __restrict__ adst,
    short* __restrict__ hThi, short* __restrict__ hTlo,
    float* __restrict__ Aarr, float* __restrict__ Barr, float* __restrict__ nsarr,
    float* __restrict__ darr, float* __restrict__ uarr, float* __restrict__ varr)
{
  const int t = threadIdx.x, lane = t & 63, wv = t >> 6;
  const int blk = blockIdx.x, bh = blk >> 5, itile = blk & 31;
  const int b = bh >> 2, hh = bh & 3;
  const int i0 = itile * 64 + wv * 16;
  const int cl = lane & 15, g = lane >> 4;

  const float* xr   = x + ((size_t)b * N_ + i0 + cl) * INF_ + g * 8;
  const size_t wo0 = (size_t)(hh * OUTF_ + cl) * INF_ + g * 8;
  const size_t wo1 = (size_t)(hh * OUTF_ + 16 + cl) * INF_ + g * 8;

  f32x4 acc0 = {0.f, 0.f, 0.f, 0.f}, acc1 = {0.f, 0.f, 0.f, 0.f};
#pragma unroll
  for (int kt = 0; kt < 4; ++kt) {
    const int kb = kt * 32;
    const f32x4 xa = *(const f32x4*)(xr + kb);
    const f32x4 xb = *(const f32x4*)(xr + kb + 4);
    bf16x8 ah, al;
    BF16_SPLIT(xa[0], ah[0], al[0]); BF16_SPLIT(xa[1], ah[1], al[1]);
    BF16_SPLIT(xa[2], ah[2], al[2]); BF16_SPLIT(xa[3], ah[3], al[3]);
    BF16_SPLIT(xb[0], ah[4], al[4]); BF16_SPLIT(xb[1], ah[5], al[5]);
    BF16_SPLIT(xb[2], ah[6], al[6]); BF16_SPLIT(xb[3], ah[7], al[7]);
    const bf16x8 b0h = *(const bf16x8*)(WThi + wo0 + kb);
    const bf16x8 b0l = *(const bf16x8*)(WTlo + wo0 + kb);
    const bf16x8 b1h = *(const bf16x8*)(WThi + wo1 + kb);
    const bf16x8 b1l = *(const bf16x8*)(WTlo + wo1 + kb);
    // (ah+al)(bh+bl) ~= ah*bh + al*bh + ah*bl  (al*bl ~ 2^-34, dropped)
    acc0 = __builtin_amdgcn_mfma_f32_16x16x32_bf16(ah, b0h, acc0, 0, 0, 0);
    acc0 = __builtin_amdgcn_mfma_f32_16x16x32_bf16(al, b0h, acc0, 0, 0, 0);
    acc0 = __builtin_amdgcn_mfma_f32_16x16x32_bf16(ah, b0l, acc0, 0, 0, 0);
    acc1 = __builtin_amdgcn_mfma_f32_16x16x32_bf16(ah, b1h, acc1, 0, 0, 0);
    acc1 = __builtin_amdgcn_mfma_f32_16x16x32_bf16(al, b1h, acc1, 0, 0, 0);
    acc1 = __builtin_amdgcn_mfma_f32_16x16x32_bf16(ah, b1l, acc1, 0, 0, 0);
  }

  // hT[bh][c][j]: C-frag rows (l>>4)*4+q are consecutive j -> 8B packed stores
  bf16x4 h0h, h0l, h1h, h1l;
  BF16_SPLIT(acc0[0], h0h[0], h0l[0]); BF16_SPLIT(acc0[1], h0h[1], h0l[1]);
  BF16_SPLIT(acc0[2], h0h[2], h0l[2]); BF16_SPLIT(acc0[3], h0h[3], h0l[3]);
  BF16_SPLIT(acc1[0], h1h[0], h1l[0]); BF16_SPLIT(acc1[1], h1h[1], h1l[1]);
  BF16_SPLIT(acc1[2], h1h[2], h1l[2]); BF16_SPLIT(acc1[3], h1h[3], h1l[3]);
  const size_t jw = (size_t)i0 + g * 4;
  const size_t c0 = ((size_t)bh * OUTF_ + cl) * N_ + jw;
  const size_t c1 = ((size_t)bh * OUTF_ + 16 + cl) * N_ + jw;
  *(bf16x4*)(hThi + c0) = h0h;
  *(bf16x4*)(hTlo + c0) = h0l;
  *(bf16x4*)(hThi + c1) = h1h;
  *(bf16x4*)(hTlo + c1) = h1l;

  // s_i = h_i . a_src, d_i = h_i . a_dst  (reduce over col dim = 16 lanes)
  const float as0 = asrc[hh * OUTF_ + cl], as1 = asrc[hh * OUTF_ + 16 + cl];
  const float ad0 = adst[hh * OUTF_ + cl], ad1 = adst[hh * OUTF_ + 16 + cl];
  float es0 = acc0[0] * as0 + acc1[0] * as1;
  float es1 = acc0[1] * as0 + acc1[1] * as1;
  float es2 = acc0[2] * as0 + acc1[2] * as1;
  float es3 = acc0[3] * as0 + acc1[3] * as1;
  float ed0 = acc0[0] * ad0 + acc1[0] * ad1;
  float ed1 = acc0[1] * ad0 + acc1[1] * ad1;
  float ed2 = acc0[2] * ad0 + acc1[2] * ad1;
  float ed3 = acc0[3] * ad0 + acc1[3] * ad1;
#pragma unroll
  for (int m = 1; m <= 8; m <<= 1) {
    es0 += __shfl_xor(es0, m); es1 += __shfl_xor(es1, m);
    es2 += __shfl_xor(es2, m); es3 += __shfl_xor(es3, m);
    ed0 += __shfl_xor(ed0, m); ed1 += __shfl_xor(ed1, m);
    ed2 += __shfl_xor(ed2, m); ed3 += __shfl_xor(ed3, m);
  }
  if (cl < 4) {
    const float s  = cl == 0 ? es0 : cl == 1 ? es1 : cl == 2 ? es2 : es3;
    const float dd = cl == 0 ? ed0 : cl == 1 ? ed1 : cl == 2 ? ed2 : ed3;
    const size_t ri = (size_t)bh * N_ + i0 + g * 4 + cl;
    Aarr[ri]  = expf(s);
    Barr[ri]  = expf(ALPHA_ * s);
    nsarr[ri] = -s;
    darr[ri]  = dd;
    uarr[ri]  = expf(dd);
    varr[ri]  = expf(ALPHA_ * dd);
  }
}

// ---------------- K3: fused masked-softmax @ h via MFMA, LDS-staged ----------------
// R6/R8 were VMEM-instruction-bound (~11 global b128/wave-iter, 4x inter-wave
// duplicate -> T~2800cyc). Now: per-block LDS double-buffer of each 32-j tile
// (h 4KB XOR-swizzled + duv 384B + masks 256B); global VMEM drops to ~2
// instr/wave-iter (reg-staged T14 split: load early, ds_write after compute).
#define TILE_DUV_ 4096
#define TILE_MSK_ 4480
#define TILE_SZ_  4736

__global__ __launch_bounds__(256, 4) void k_attn(const short* __restrict__ hThi,
    const short* __restrict__ hTlo, const uint32_t* __restrict__ bits32,
    const float* __restrict__ Aarr, const float* __restrict__ Barr,
    const float* __restrict__ nsarr, const float* __restrict__ darr,
    const float* __restrict__ uarr, const float* __restrict__ varr,
    float* __restrict__ out)
{
  __shared__ __align__(16) char smem[2][TILE_SZ_];

  const int t = threadIdx.x, lane = t & 63, wv = t >> 6;
  const int blk = blockIdx.x, bh = blk >> 5, itile = blk & 31;
  const int b = bh >> 2, hh = bh & 3;
  const int i0b = itile * 64;
  const int i0 = i0b + wv * 16;          // 16 rows per wave
  const int cl = lane & 15, g = lane >> 4;
  const int jb = g * 8;

  const size_t rbase = (size_t)bh * N_;
  const float Ai  = Aarr[rbase + i0 + cl];
  const float Bi  = Barr[rbase + i0 + cl];
  const float nsi = nsarr[rbase + i0 + cl];

  // ---- staging roles (fixed per thread) ----
  // h: thread t covers LDS row c=t>>3, 16B slot s=t&7 (s<4 -> hi, else lo)
  const int sc = t >> 3, ss = t & 7;
  const short* hsrc = (ss < 4 ? hThi + ss * 8 : hTlo + (ss - 4) * 8)
                      + ((size_t)bh * OUTF_ + sc) * N_;
  const int h_dst = sc * 128 + ((ss * 16) ^ ((sc & 7) << 4));   // write-side swizzle
  const float* duvsrc = (t < 8 ? darr : (t < 16 ? uarr : varr)) + rbase + (t & 7) * 4;
  const uint32_t* msksrc = bits32 + (size_t)(i0b + (t & 63)) * (N_ / 32);

  // ---- compute-side LDS offsets ----
  const int swz = (cl & 7) << 4;
  const int off_h0h = cl * 128 + ((g * 16) ^ swz);
  const int off_h0l = cl * 128 + ((64 + g * 16) ^ swz);
  const int off_h1h = (16 + cl) * 128 + ((g * 16) ^ swz);
  const int off_h1l = (16 + cl) * 128 + ((64 + g * 16) ^ swz);
  const int off_d0 = TILE_DUV_ + g * 32,       off_d1 = off_d0 + 16;
  const int off_u0 = TILE_DUV_ + 128 + g * 32, off_u1 = off_u0 + 16;
  const int off_v0 = TILE_DUV_ + 256 + g * 32, off_v1 = off_v0 + 16;
  const int off_m  = TILE_MSK_ + (wv * 16 + cl) * 4;

  f32x4 acc0 = {0.f, 0.f, 0.f, 0.f}, acc1 = {0.f, 0.f, 0.f, 0.f};
  float z = 0.f;
  bf16x8 sth; f32x4 stduv; uint32_t stmsk;

#define STAGE_LOAD(JT) {                                        \
    sth = *(const bf16x8*)(hsrc + (JT) * 32);                   \
    if (t < 24) stduv = *(const f32x4*)(duvsrc + (JT) * 32);    \
    if (t >= 64 && t < 128) stmsk = msksrc[(JT)]; }

#define STAGE_WRITE(BI) {                                                   \
    char* sb_ = smem[BI];                                                   \
    *(bf16x8*)(sb_ + h_dst) = sth;                                          \
    if (t < 24) *(f32x4*)(sb_ + TILE_DUV_ + t * 16) = stduv;                \
    if (t >= 64 && t < 128) *(uint32_t*)(sb_ + TILE_MSK_ + (t - 64) * 4) = stmsk; }

#define WGEN(E, DE, UE, VE) {                                   \
    const bool c_ = (DE) > nsi;                                 \
    float w_ = (c_ ? Ai : Bi) * (c_ ? (UE) : (VE));             \
    w_ = ((wsh >> (E)) & 1u) ? w_ : 0.f;                        \
    const uint32_t hi_ = __float_as_uint(w_) & 0xffff0000u;     \
    whi[E] = (short)(hi_ >> 16);                                \
    wlo[E] = (short)(__float_as_uint(w_ - __uint_as_float(hi_)) >> 16); \
    z += w_; }

#define COMPUTE(BI) {                                                 \
    const char* sb_ = smem[BI];                                       \
    const f32x4 d0 = *(const f32x4*)(sb_ + off_d0);                   \
    const f32x4 d1 = *(const f32x4*)(sb_ + off_d1);                   \
    const f32x4 u0 = *(const f32x4*)(sb_ + off_u0);                   \
    const f32x4 u1 = *(const f32x4*)(sb_ + off_u1);                   \
    const f32x4 v0 = *(const f32x4*)(sb_ + off_v0);                   \
    const f32x4 v1 = *(const f32x4*)(sb_ + off_v1);                   \
    const bf16x8 h0h = *(const bf16x8*)(sb_ + off_h0h);               \
    const bf16x8 h0l = *(const bf16x8*)(sb_ + off_h0l);               \
    const bf16x8 h1h = *(const bf16x8*)(sb_ + off_h1h);               \
    const bf16x8 h1l = *(const bf16x8*)(sb_ + off_h1l);               \
    const uint32_t wsh = (*(const uint32_t*)(sb_ + off_m)) >> jb;     \
    bf16x8 whi, wlo;                                                  \
    WGEN(0, d0[0], u0[0], v0[0])                                      \
    WGEN(1, d0[1], u0[1], v0[1])                                      \
    WGEN(2, d0[2], u0[2], v0[2])                                      \
    WGEN(3, d0[3], u0[3], v0[3])                                      \
    WGEN(4, d1[0], u1[0], v1[0])                                      \
    WGEN(5, d1[1], u1[1], v1[1])                                      \
    WGEN(6, d1[2], u1[2], v1[2])                                      \
    WGEN(7, d1[3], u1[3], v1[3])                                      \
    acc0 = __builtin_amdgcn_mfma_f32_16x16x32_bf16(whi, h0h, acc0, 0, 0, 0); \
    acc0 = __builtin_amdgcn_mfma_f32_16x16x32_bf16(wlo, h0h, acc0, 0, 0, 0); \
    acc0 = __builtin_amdgcn_mfma_f32_16x16x32_bf16(whi, h0l, acc0, 0, 0, 0); \
    acc1 = __builtin_amdgcn_mfma_f32_16x16x32_bf16(whi, h1h, acc1, 0, 0, 0); \
    acc1 = __builtin_amdgcn_mfma_f32_16x16x32_bf16(wlo, h1h, acc1, 0, 0, 0); \
    acc1 = __builtin_amdgcn_mfma_f32_16x16x32_bf16(whi, h1l, acc1, 0, 0, 0); }

  STAGE_LOAD(0)
  STAGE_WRITE(0)
  __syncthreads();
#pragma unroll 1
  for (int jt = 0; jt < N_ / 32; jt += 2) {
    STAGE_LOAD(jt + 1)
    COMPUTE(0)
    STAGE_WRITE(1)
    __syncthreads();
    if (jt + 2 < N_ / 32) STAGE_LOAD(jt + 2)
    COMPUTE(1)
    if (jt + 2 < N_ / 32) STAGE_WRITE(0)
    __syncthreads();
  }
#undef COMPUTE
#undef WGEN
#undef STAGE_WRITE
#undef STAGE_LOAD

  // fold z over the 4 j-groups within the wave (row = cl)
  z += __shfl_xor(z, 16);
  z += __shfl_xor(z, 32);

  // epilogue: C-frag row = g*4+q, col = cl; fetch that row's Z via shfl
  float* op = out + ((size_t)b * N_ + i0) * (H_ * OUTF_) + hh * OUTF_;
#pragma unroll
  for (int q = 0; q < 4; ++q) {
    const float zr = __shfl(z, g * 4 + q);
    const float inv = 1.0f / zr;
    op[(size_t)(g * 4 + q) * (H_ * OUTF_) + cl]      = acc0[q] * inv;
    op[(size_t)(g * 4 + q) * (H_ * OUTF_) + 16 + cl] = acc1[q] * inv;
  }
}

extern "C" void kernel_launch(void* const* d_in, const int* in_sizes, int n_in,
                              void* d_out, int out_size, void* d_ws, size_t ws_size,
                              hipStream_t stream) {
  const float* x    = (const float*)d_in[0];
  const int*   adj  = (const int*)d_in[1];
  const float* W    = (const float*)d_in[2];
  const float* asrc = (const float*)d_in[3];
  const float* adst = (const float*)d_in[4];
  float* out = (float*)d_out;

  char* ws = (char*)d_ws;
  short* hThi = (short*)ws;                                         // 4 MB
  short* hTlo = (short*)(ws + 4194304);                             // 4 MB
  unsigned long long* bits = (unsigned long long*)(ws + 8388608);   // 512 KB
  float* Aarr  = (float*)(ws + 8912896);
  float* Barr  = Aarr  + BH_ * N_;
  float* nsarr = Barr  + BH_ * N_;
  float* darr  = nsarr + BH_ * N_;
  float* uarr  = darr  + BH_ * N_;
  float* varr  = uarr  + BH_ * N_;
  short* WThi  = (short*)(ws + 10485760);                           // 32 KB
  short* WTlo  = (short*)(ws + 10518528);                           // 32 KB

  hipLaunchKernelGGL(k_wt, dim3(H_), dim3(INF_), 0, stream, W, WThi, WTlo);
  hipLaunchKernelGGL(k_pack_adj, dim3(N_), dim3(256), 0, stream, adj, bits);
  hipLaunchKernelGGL(k_feat, dim3(BH_ * 32), dim3(256), 0, stream,
                     x, WThi, WTlo, asrc, adst, hThi, hTlo,
                     Aarr, Barr, nsarr, darr, uarr, varr);
  hipLaunchKernelGGL(k_attn, dim3(BH_ * 32), dim3(256), 0, stream,
                     hThi, hTlo, (const uint32_t*)bits,
                     Aarr, Barr, nsarr, darr, uarr, varr, out);
}